// Round 4
// baseline (1002.915 us; speedup 1.0000x reference)
//
#include <hip/hip_runtime.h>
#include <cmath>

// Problem constants
#define BATCH 4
#define SEQ   2048
#define EMB   2048
#define NH    16
#define HD    128
#define MDIM  (BATCH*SEQ)   // 8192
#define KDIM  EMB           // 2048
#define NDIM  EMB           // 2048

typedef __bf16 bf16x8 __attribute__((ext_vector_type(8)));
typedef float  f32x4  __attribute__((ext_vector_type(4)));

__device__ __forceinline__ ushort bf16rne(float f) {
  unsigned u = __builtin_bit_cast(unsigned, f);
  u += 0x7fffu + ((u >> 16) & 1u);
  return (ushort)(u >> 16);
}

// global -> LDS direct DMA, 16 bytes per lane.
// LDS dest must be wave-uniform base; HW adds lane*16.
__device__ __forceinline__ void gld_lds16(const ushort* g, ushort* l) {
  __builtin_amdgcn_global_load_lds(
      (const __attribute__((address_space(1))) unsigned int*)g,
      (__attribute__((address_space(3))) unsigned int*)l, 16, 0, 0);
}

// ---------------- fp32 -> bf16 convert (vector x4) ----------------
__global__ __launch_bounds__(256) void cvt_bf16(const float* __restrict__ in,
                                                ushort* __restrict__ out) {
  int i = (blockIdx.x * 256 + threadIdx.x) * 4;
  float4 v = *(const float4*)(in + i);
  ushort4 o;
  o.x = bf16rne(v.x); o.y = bf16rne(v.y); o.z = bf16rne(v.z); o.w = bf16rne(v.w);
  *(ushort4*)(out + i) = o;
}

// ---------------- NT GEMM: C[M,N] = A[M,K] * B[N,K]^T + bias ----------------
// R4: T3 minimum-2-phase double-buffer. Issue global_load_lds for tile t+1
// BEFORE computing tile t; single barrier per K-step -> the compiler's
// vmcnt(0)-before-barrier drain lands after compute, so DMA overlaps MFMA.
// (R1 failed because issue->drain->compute was serial; R2's reg-prefetch
//  spilled. This structure = m230/m248v2's verified 682 TF recipe.)
// MODE 0: fp32 plain row-major [M,N]
// MODE 1: bf16 to [B,H,S,D]   (m = b*S+s, n = h*D+d)
// MODE 2: bf16 to [B,H,D,S]   (transposed store via LDS, scratch aliased on As)
template<int MODE>
__global__ __launch_bounds__(256, 2)
void gemm_nt(const ushort* __restrict__ A, const ushort* __restrict__ Bm,
             const float* __restrict__ bias, void* __restrict__ out) {
  __shared__ ushort As[2][128 * 64];   // linear row-major [128][64], dbuf
  __shared__ ushort Bs[2][128 * 64];

  const int tid  = threadIdx.x;
  const int wave = tid >> 6, lane = tid & 63;
  const int l15  = lane & 15, quad = lane >> 4;
  const int m0 = blockIdx.x * 128, n0 = blockIdx.y * 128;
  const int wr = (wave >> 1) * 64, wc = (wave & 1) * 64;

  const f32x4 zero4 = {0.f, 0.f, 0.f, 0.f};
  f32x4 acc[4][4];
#pragma unroll
  for (int i = 0; i < 4; ++i)
#pragma unroll
    for (int j = 0; j < 4; ++j) acc[i][j] = zero4;

  // staging: chunk L = it*256 + tid; row = L>>3, col8 = (L&7)*8.
  // LDS ushort offset = L*8 = wave-uniform (it*256 + (tid&~63))*8 + lane*8.
  const int srow = tid >> 3, sc8 = (tid & 7) * 8;
  const int Lw   = tid & ~63;

  auto STAGE = [&](int buf, int kk) {
#pragma unroll
    for (int it = 0; it < 4; ++it) {
      gld_lds16(A  + (size_t)(m0 + it*32 + srow) * KDIM + kk + sc8,
                &As[buf][(it*256 + Lw) * 8]);
      gld_lds16(Bm + (size_t)(n0 + it*32 + srow) * KDIM + kk + sc8,
                &Bs[buf][(it*256 + Lw) * 8]);
    }
  };

  STAGE(0, 0);
  __syncthreads();                       // drains vmcnt -> tile0 ready
  int cur = 0;
  for (int kk = 0; kk < KDIM; kk += 64) {
    if (kk + 64 < KDIM) STAGE(cur ^ 1, kk + 64);   // issue next tile
    const ushort* Ab = As[cur];
    const ushort* Bb = Bs[cur];
#pragma unroll
    for (int ks = 0; ks < 2; ++ks) {
      bf16x8 af[4], bfr[4];
#pragma unroll
      for (int i = 0; i < 4; ++i)
        af[i] = __builtin_bit_cast(bf16x8,
                  *(const int4*)(Ab + (wr + i*16 + l15) * 64 + ks*32 + quad*8));
#pragma unroll
      for (int j = 0; j < 4; ++j)
        bfr[j] = __builtin_bit_cast(bf16x8,
                  *(const int4*)(Bb + (wc + j*16 + l15) * 64 + ks*32 + quad*8));
#pragma unroll
      for (int i = 0; i < 4; ++i)
#pragma unroll
        for (int j = 0; j < 4; ++j)
          acc[i][j] = __builtin_amdgcn_mfma_f32_16x16x32_bf16(af[i], bfr[j], acc[i][j], 0, 0, 0);
    }
    __syncthreads();   // drains next-tile DMA (overlapped with MFMA above)
    cur ^= 1;
  }

  // Epilogue. C/D layout: col = lane&15, row = quad*4 + r  (m89/m91 verified)
  if constexpr (MODE == 0) {
    float* O = (float*)out;
#pragma unroll
    for (int i = 0; i < 4; ++i)
#pragma unroll
      for (int j = 0; j < 4; ++j) {
        int n = n0 + wc + j*16 + l15;
        float bb = bias[n];
#pragma unroll
        for (int r = 0; r < 4; ++r) {
          int m = m0 + wr + i*16 + quad*4 + r;
          O[(size_t)m * NDIM + n] = acc[i][j][r] + bb;
        }
      }
  } else if constexpr (MODE == 1) {
    ushort* O = (ushort*)out;
#pragma unroll
    for (int i = 0; i < 4; ++i)
#pragma unroll
      for (int j = 0; j < 4; ++j) {
        int n = n0 + wc + j*16 + l15;
        float bb = bias[n];
        int h = n >> 7, d = n & 127;
#pragma unroll
        for (int r = 0; r < 4; ++r) {
          int m = m0 + wr + i*16 + quad*4 + r;
          int b = m >> 11, srow2 = m & 2047;
          O[(((size_t)(b*NH + h) * SEQ + srow2) << 7) + d] = bf16rne(acc[i][j][r] + bb);
        }
      }
  } else {  // MODE 2: [B,H,D,S] via per-wave LDS 16x16 transpose
    // scratch aliased onto As (dead after K-loop; per-wave region, in-wave
    // ds ordering makes write->read safe, same as the original Tt)
    float* TtF = (float*)&As[0][0];      // [4][16][17] floats = 4352 B
    ushort* O = (ushort*)out;
    const int h = n0 >> 7;   // N-tile(128) == one head
#pragma unroll
    for (int i = 0; i < 4; ++i)
#pragma unroll
      for (int j = 0; j < 4; ++j) {
        int n = n0 + wc + j*16 + l15;
        float bb = bias[n];
#pragma unroll
        for (int r = 0; r < 4; ++r)
          TtF[(wave*16 + l15)*17 + quad*4 + r] = acc[i][j][r] + bb; // [d_loc][s_loc]
#pragma unroll
        for (int r = 0; r < 4; ++r) {
          int dl = quad*4 + r, sl = l15;
          float v = TtF[(wave*16 + dl)*17 + sl];
          int m = m0 + wr + i*16 + sl;
          int b = m >> 11, srow2 = m & 2047;
          int d = wc + j*16 + dl;
          O[((size_t)(b*NH + h) * HD + d) * SEQ + srow2] = bf16rne(v);
        }
      }
  }
}

// ---------------- fused attention (no-max online softmax) ----------------
// Qh,Kh: bf16 [B,H,S,D]; Vt: bf16 [B,H,D,S]; noise fp32 [B,S,E];
// ctxn: bf16 [B*S, E] = softmax(QK^T * scale) V + noise*ns
//
// R4: T3 minimum-2-phase dbuf K/V via global_load_lds; source addresses
// pre-swizzled (rule #21: linear dest + inverse-swz source + swz read; the
// XOR is an involution). Ps stays single-buffered (wave-private).
// One barrier per K-tile. T5 setprio around MFMA clusters (attn-proven).
__global__ __launch_bounds__(256, 2)
void attn_kernel(const ushort* __restrict__ Qh, const ushort* __restrict__ Kh,
                 const ushort* __restrict__ Vt, const float* __restrict__ noise,
                 ushort* __restrict__ ctxn, float scale, float ns) {
  __shared__ ushort Ks[2][64 * 128];   // [k_row][d], row 256B, slot-XOR swizzled
  __shared__ ushort Vs[2][128 * 64];   // [d][k_col], row 128B, swizzled
  __shared__ ushort Ps[64 * 64];       // [q][k],    row 128B, swizzled

  const int tid  = threadIdx.x;
  const int wave = tid >> 6, lane = tid & 63;
  const int l15  = lane & 15, quad = lane >> 4;
  const int q0 = blockIdx.x * 64;
  const int bh = blockIdx.y;                  // b*NH + h
  const int b  = bh >> 4, h = bh & 15;

  const ushort* Kb = Kh + (size_t)bh * SEQ * HD;
  const ushort* Vb = Vt + (size_t)bh * HD * SEQ;

  // staging coords (chunk L = it*256 + tid, linear LDS dest = L*16B)
  const int rkr = tid >> 4, rks = tid & 15;   // K: row = it*16 + rkr, slot = rks
  const int rvr = tid >> 3, rvs = tid & 7;    // V: row = it*32 + rvr, slot = rvs
  const int Lw  = tid & ~63;

  // source col pre-swizzled: linear slot s receives logical slot s^(row&7)
  auto STAGE = [&](int buf, int k0) {
#pragma unroll
    for (int it = 0; it < 4; ++it)
      gld_lds16(Kb + (size_t)(k0 + it*16 + rkr) * HD + (rks ^ (rkr & 7)) * 8,
                &Ks[buf][(it*256 + Lw) * 8]);
#pragma unroll
    for (int it = 0; it < 4; ++it)
      gld_lds16(Vb + (size_t)(it*32 + rvr) * SEQ + k0 + (rvs ^ (rvr & 7)) * 8,
                &Vs[buf][(it*256 + Lw) * 8]);
  };

  // Q fragments for this wave's 16-row strip, held in registers
  bf16x8 qf[4];
  {
    const int qrow = q0 + wave*16 + l15;
    const ushort* qp = Qh + ((size_t)bh * SEQ + qrow) * HD;
#pragma unroll
    for (int ks = 0; ks < 4; ++ks)
      qf[ks] = __builtin_bit_cast(bf16x8, *(const int4*)(qp + ks*32 + quad*8));
  }

  const f32x4 zero4 = {0.f, 0.f, 0.f, 0.f};
  f32x4 o[8];
#pragma unroll
  for (int nb = 0; nb < 8; ++nb) o[nb] = zero4;
  float rs[4] = {0.f, 0.f, 0.f, 0.f};

  STAGE(0, 0);
  __syncthreads();                       // tile0 ready
  int cur = 0;
  for (int k0 = 0; k0 < SEQ; k0 += 64) {
    if (k0 + 64 < SEQ) STAGE(cur ^ 1, k0 + 64);   // overlaps compute below
    const ushort* Kc = Ks[cur];
    const ushort* Vc = Vs[cur];

    // QK^T for this wave's strip -> exp -> P (LDS round trip)
#pragma unroll
    for (int ct = 0; ct < 4; ++ct) {
      f32x4 s = zero4;
      const int kr = ct*16 + l15;
      __builtin_amdgcn_s_setprio(1);
#pragma unroll
      for (int ks = 0; ks < 4; ++ks) {
        bf16x8 kf = __builtin_bit_cast(bf16x8,
            *(const int4*)(Kc + kr * 128 + ((ks*32 + quad*8) ^ ((kr & 7) << 3))));
        s = __builtin_amdgcn_mfma_f32_16x16x32_bf16(qf[ks], kf, s, 0, 0, 0);
      }
      __builtin_amdgcn_s_setprio(0);
#pragma unroll
      for (int r = 0; r < 4; ++r) {
        float p = __expf(s[r] * scale);
        rs[r] += p;
        int pr = wave*16 + quad*4 + r;
        int pc = ct*16 + l15;
        Ps[pr * 64 + (pc ^ ((pr & 7) << 3))] = bf16rne(p);
      }
    }

    // PV: o[q, d] += P[q, k] V[k, d]
    __builtin_amdgcn_s_setprio(1);
#pragma unroll
    for (int ks2 = 0; ks2 < 2; ++ks2) {
      const int par = wave*16 + l15;
      bf16x8 pa = __builtin_bit_cast(bf16x8,
          *(const int4*)(&Ps[par * 64 + ((ks2*32 + quad*8) ^ ((par & 7) << 3))]));
#pragma unroll
      for (int nb = 0; nb < 8; ++nb) {
        const int vr = nb*16 + l15;
        bf16x8 vb = __builtin_bit_cast(bf16x8,
            *(const int4*)(Vc + vr * 64 + ((ks2*32 + quad*8) ^ ((vr & 7) << 3))));
        o[nb] = __builtin_amdgcn_mfma_f32_16x16x32_bf16(pa, vb, o[nb], 0, 0, 0);
      }
    }
    __builtin_amdgcn_s_setprio(0);
    __syncthreads();   // drains next-tile DMA (overlapped) + LDS reads done
    cur ^= 1;
  }

  // row sums: reduce across the 16 lanes of each quad
#pragma unroll
  for (int r = 0; r < 4; ++r) {
    float v = rs[r];
    v += __shfl_xor(v, 1);
    v += __shfl_xor(v, 2);
    v += __shfl_xor(v, 4);
    v += __shfl_xor(v, 8);
    rs[r] = v;
  }

  // epilogue: normalize, add DP noise, emit bf16 ctx in [B*S, E] layout
#pragma unroll
  for (int r = 0; r < 4; ++r) {
    float inv = 1.0f / rs[r];
    int sg = q0 + wave*16 + quad*4 + r;
    size_t rowbase = ((size_t)(b * SEQ + sg)) * EMB + h * HD;
#pragma unroll
    for (int nb = 0; nb < 8; ++nb) {
      int e = nb*16 + l15;
      float val = o[nb][r] * inv + noise[rowbase + e] * ns;
      ctxn[rowbase + e] = bf16rne(val);
    }
  }
}

extern "C" void kernel_launch(void* const* d_in, const int* in_sizes, int n_in,
                              void* d_out, int out_size, void* d_ws, size_t ws_size,
                              hipStream_t stream) {
  const float* query = (const float*)d_in[0];
  const float* key_t = (const float*)d_in[1];
  const float* value = (const float*)d_in[2];
  const float* Wq = (const float*)d_in[3];
  const float* bq = (const float*)d_in[4];
  const float* Wk = (const float*)d_in[5];
  const float* bk = (const float*)d_in[6];
  const float* Wv = (const float*)d_in[7];
  const float* bv = (const float*)d_in[8];
  const float* Wo = (const float*)d_in[9];
  const float* bo = (const float*)d_in[10];
  const float* noise = (const float*)d_in[11];

  const size_t SZ_ACT = (size_t)MDIM * KDIM * 2;  // 33,554,432 B
  const size_t SZ_W   = (size_t)NDIM * KDIM * 2;  //  8,388,608 B
  const size_t need_full = 7 * SZ_ACT + 4 * SZ_W; // 256 MB

  char* p = (char*)d_ws;
  ushort *qb, *kb;
  if (ws_size >= need_full) {
    qb = (ushort*)p; p += SZ_ACT;
    kb = (ushort*)p; p += SZ_ACT;
  } else {
    // overlay q/k bf16 inputs on d_out (exactly 64 MB); consumed before final GEMM
    qb = (ushort*)d_out;
    kb = (ushort*)((char*)d_out + SZ_ACT);
  }
  ushort* vb   = (ushort*)p; p += SZ_ACT;
  ushort* wqb  = (ushort*)p; p += SZ_W;
  ushort* wkb  = (ushort*)p; p += SZ_W;
  ushort* wvb  = (ushort*)p; p += SZ_W;
  ushort* wob  = (ushort*)p; p += SZ_W;
  ushort* Qh   = (ushort*)p; p += SZ_ACT;
  ushort* Kh   = (ushort*)p; p += SZ_ACT;
  ushort* Vt   = (ushort*)p; p += SZ_ACT;
  ushort* ctxn = (ushort*)p; p += SZ_ACT;

  const int nAct = MDIM * KDIM;          // 16,777,216
  const int nW   = NDIM * KDIM;          //  4,194,304
  const float NS = (float)sqrt(2.0 * log(1.25 / 1e-5));
  const float SCALE = (float)(1.0 / sqrt((double)HD));

  cvt_bf16<<<dim3(nAct / 1024), dim3(256), 0, stream>>>(query, qb);
  cvt_bf16<<<dim3(nAct / 1024), dim3(256), 0, stream>>>(key_t, kb);
  cvt_bf16<<<dim3(nAct / 1024), dim3(256), 0, stream>>>(value, vb);
  cvt_bf16<<<dim3(nW / 1024),   dim3(256), 0, stream>>>(Wq, wqb);
  cvt_bf16<<<dim3(nW / 1024),   dim3(256), 0, stream>>>(Wk, wkb);
  cvt_bf16<<<dim3(nW / 1024),   dim3(256), 0, stream>>>(Wv, wvb);
  cvt_bf16<<<dim3(nW / 1024),   dim3(256), 0, stream>>>(Wo, wob);

  dim3 ggrid(MDIM / 128, NDIM / 128);   // 64 x 16
  gemm_nt<1><<<ggrid, dim3(256), 0, stream>>>(qb, wqb, bq, (void*)Qh);
  gemm_nt<1><<<ggrid, dim3(256), 0, stream>>>(kb, wkb, bk, (void*)Kh);
  gemm_nt<2><<<ggrid, dim3(256), 0, stream>>>(vb, wvb, bv, (void*)Vt);

  attn_kernel<<<dim3(SEQ / 64, BATCH * NH), dim3(256), 0, stream>>>(
      Qh, Kh, Vt, noise, ctxn, SCALE, NS);

  gemm_nt<0><<<ggrid, dim3(256), 0, stream>>>(ctxn, wob, bo, d_out);
}

// Round 5
// 840.673 us; speedup vs baseline: 1.1930x; 1.1930x over previous
//
#include <hip/hip_runtime.h>
#include <cmath>

// Problem constants
#define BATCH 4
#define SEQ   2048
#define EMB   2048
#define NH    16
#define HD    128
#define MDIM  (BATCH*SEQ)   // 8192
#define KDIM  EMB           // 2048
#define NDIM  EMB           // 2048

typedef __bf16 bf16x8 __attribute__((ext_vector_type(8)));
typedef float  f32x4  __attribute__((ext_vector_type(4)));

__device__ __forceinline__ ushort bf16rne(float f) {
  unsigned u = __builtin_bit_cast(unsigned, f);
  u += 0x7fffu + ((u >> 16) & 1u);
  return (ushort)(u >> 16);
}

// ---------------- fp32 -> bf16 convert (vector x4) ----------------
__global__ __launch_bounds__(256) void cvt_bf16(const float* __restrict__ in,
                                                ushort* __restrict__ out) {
  int i = (blockIdx.x * 256 + threadIdx.x) * 4;
  float4 v = *(const float4*)(in + i);
  ushort4 o;
  o.x = bf16rne(v.x); o.y = bf16rne(v.y); o.z = bf16rne(v.z); o.w = bf16rne(v.w);
  *(ushort4*)(out + i) = o;
}

// ---------------- NT GEMM: C[M,N] = A[M,K] * B[N,K]^T + bias ----------------
// Verified 137us/dispatch version: padded LDS + register staging (compiler
// hoists next-tile loads across the barrier -> implicit pipelining; 3-4
// blocks/CU). SESSION RULE (R1/R2/R4 all regressed): TLP beats grafted
// pipelining here — gload_lds 2ph dbuf = 165us (2 blocks/CU), reg-prefetch
// spilled. Do not re-introduce.
// MODE 0: fp32 plain row-major [M,N]
// MODE 1: bf16 to [B,H,S,D]   (m = b*S+s, n = h*D+d)
// MODE 2: bf16 to [B,H,D,S]   (transposed store via LDS)
template<int MODE>
__global__ __launch_bounds__(256, 2)
void gemm_nt(const ushort* __restrict__ A, const ushort* __restrict__ Bm,
             const float* __restrict__ bias, void* __restrict__ out) {
  __shared__ ushort As[128][72];   // 64 + 8 pad: row stride 144B -> <=2-way bank alias
  __shared__ ushort Bs[128][72];

  const int tid  = threadIdx.x;
  const int wave = tid >> 6, lane = tid & 63;
  const int l15  = lane & 15, quad = lane >> 4;
  const int m0 = blockIdx.x * 128, n0 = blockIdx.y * 128;
  const int wr = (wave >> 1) * 64, wc = (wave & 1) * 64;

  const f32x4 zero4 = {0.f, 0.f, 0.f, 0.f};
  f32x4 acc[4][4];
#pragma unroll
  for (int i = 0; i < 4; ++i)
#pragma unroll
    for (int j = 0; j < 4; ++j) acc[i][j] = zero4;

  for (int kk = 0; kk < KDIM; kk += 64) {
#pragma unroll
    for (int it = 0; it < 4; ++it) {
      int L = it * 256 + tid;            // 0..1023 chunk id (8 bf16 per chunk)
      int row = L >> 3, c8 = (L & 7) * 8;
      int4 va = *(const int4*)(A  + (size_t)(m0 + row) * KDIM + kk + c8);
      int4 vb = *(const int4*)(Bm + (size_t)(n0 + row) * KDIM + kk + c8);
      *(int4*)(&As[row][c8]) = va;
      *(int4*)(&Bs[row][c8]) = vb;
    }
    __syncthreads();
#pragma unroll
    for (int ks = 0; ks < 2; ++ks) {
      bf16x8 af[4], bfr[4];
#pragma unroll
      for (int i = 0; i < 4; ++i)
        af[i] = __builtin_bit_cast(bf16x8, *(const int4*)(&As[wr + i*16 + l15][ks*32 + quad*8]));
#pragma unroll
      for (int j = 0; j < 4; ++j)
        bfr[j] = __builtin_bit_cast(bf16x8, *(const int4*)(&Bs[wc + j*16 + l15][ks*32 + quad*8]));
#pragma unroll
      for (int i = 0; i < 4; ++i)
#pragma unroll
        for (int j = 0; j < 4; ++j)
          acc[i][j] = __builtin_amdgcn_mfma_f32_16x16x32_bf16(af[i], bfr[j], acc[i][j], 0, 0, 0);
    }
    __syncthreads();
  }

  // Epilogue. C/D layout: col = lane&15, row = quad*4 + r  (m89/m91 verified)
  if constexpr (MODE == 0) {
    float* O = (float*)out;
#pragma unroll
    for (int i = 0; i < 4; ++i)
#pragma unroll
      for (int j = 0; j < 4; ++j) {
        int n = n0 + wc + j*16 + l15;
        float bb = bias[n];
#pragma unroll
        for (int r = 0; r < 4; ++r) {
          int m = m0 + wr + i*16 + quad*4 + r;
          O[(size_t)m * NDIM + n] = acc[i][j][r] + bb;
        }
      }
  } else if constexpr (MODE == 1) {
    ushort* O = (ushort*)out;
#pragma unroll
    for (int i = 0; i < 4; ++i)
#pragma unroll
      for (int j = 0; j < 4; ++j) {
        int n = n0 + wc + j*16 + l15;
        float bb = bias[n];
        int h = n >> 7, d = n & 127;
#pragma unroll
        for (int r = 0; r < 4; ++r) {
          int m = m0 + wr + i*16 + quad*4 + r;
          int b = m >> 11, srow = m & 2047;
          O[(((size_t)(b*NH + h) * SEQ + srow) << 7) + d] = bf16rne(acc[i][j][r] + bb);
        }
      }
  } else {  // MODE 2: [B,H,D,S] via per-wave LDS 16x16 transpose
    __shared__ float Tt[4][16][17];
    ushort* O = (ushort*)out;
    const int h = n0 >> 7;   // N-tile(128) == one head
#pragma unroll
    for (int i = 0; i < 4; ++i)
#pragma unroll
      for (int j = 0; j < 4; ++j) {
        int n = n0 + wc + j*16 + l15;
        float bb = bias[n];
#pragma unroll
        for (int r = 0; r < 4; ++r)
          Tt[wave][l15][quad*4 + r] = acc[i][j][r] + bb;   // Tt[d_local][s_local]
#pragma unroll
        for (int r = 0; r < 4; ++r) {
          int dl = quad*4 + r, sl = l15;
          float v = Tt[wave][dl][sl];
          int m = m0 + wr + i*16 + sl;
          int b = m >> 11, srow = m & 2047;
          int d = wc + j*16 + dl;
          O[((size_t)(b*NH + h) * HD + d) * SEQ + srow] = bf16rne(v);
        }
      }
  }
}

// ---------------- fused attention (no-max online softmax) ----------------
// Qh,Kh: bf16 [B,H,S,D]; Vt: bf16 [B,H,D,S]; noise fp32 [B,S,E];
// ctxn: bf16 [B*S, E] = softmax(QK^T * scale) V + noise*ns
//
// R5: QBLK 64 -> 128 (8 waves, 512 threads). K/V staging + barriers per
// unit work halve; K/V cross-block refetch halves; LDS 48KB -> 3 blocks/CU
// = up to 24 waves/CU. Same 2-barrier loop, XOR swizzle (R3, -50% bank
// conflicts), setprio. NO dbuf (R4: occupancy loss > overlap gain).
__global__ __launch_bounds__(512, 2)
void attn_kernel(const ushort* __restrict__ Qh, const ushort* __restrict__ Kh,
                 const ushort* __restrict__ Vt, const float* __restrict__ noise,
                 ushort* __restrict__ ctxn, float scale, float ns) {
  __shared__ ushort Ks[64 * 128];    // [k_row][d], row 256B, swizzled
  __shared__ ushort Vs[128 * 64];    // [d][k_col], row 128B, swizzled
  __shared__ ushort Ps[128 * 64];    // [q][k],     row 128B, swizzled

  const int tid  = threadIdx.x;
  const int wave = tid >> 6, lane = tid & 63;
  const int l15  = lane & 15, quad = lane >> 4;
  const int q0 = blockIdx.x * 128;
  const int bh = blockIdx.y;                  // b*NH + h
  const int b  = bh >> 4, h = bh & 15;

  // Q fragments for this wave's 16-row strip, held in registers
  bf16x8 qf[4];
  {
    const int qrow = q0 + wave*16 + l15;
    const ushort* qp = Qh + ((size_t)bh * SEQ + qrow) * HD;
#pragma unroll
    for (int ks = 0; ks < 4; ++ks)
      qf[ks] = __builtin_bit_cast(bf16x8, *(const int4*)(qp + ks*32 + quad*8));
  }

  const f32x4 zero4 = {0.f, 0.f, 0.f, 0.f};
  f32x4 o[8];
#pragma unroll
  for (int nb = 0; nb < 8; ++nb) o[nb] = zero4;
  float rs[4] = {0.f, 0.f, 0.f, 0.f};

  for (int k0 = 0; k0 < SEQ; k0 += 64) {
    // stage K tile: 64 rows x 128 d (1024 chunks of 8 bf16, 512 threads x 2)
#pragma unroll
    for (int it = 0; it < 2; ++it) {
      int L = it * 512 + tid;
      int r = L >> 4, c8 = (L & 15) * 8;
      int4 v = *(const int4*)(Kh + ((size_t)bh * SEQ + k0 + r) * HD + c8);
      *(int4*)(&Ks[r * 128 + (c8 ^ ((r & 7) << 3))]) = v;
    }
    // stage V^T tile: 128 d-rows x 64 k (1024 chunks)
#pragma unroll
    for (int it = 0; it < 2; ++it) {
      int L = it * 512 + tid;
      int r = L >> 3, c8 = (L & 7) * 8;
      int4 v = *(const int4*)(Vt + ((size_t)bh * HD + r) * SEQ + k0 + c8);
      *(int4*)(&Vs[r * 64 + (c8 ^ ((r & 7) << 3))]) = v;
    }
    __syncthreads();

    // QK^T for this wave's strip -> exp -> P (LDS round trip)
#pragma unroll
    for (int ct = 0; ct < 4; ++ct) {
      f32x4 s = zero4;
      const int kr = ct*16 + l15;
      __builtin_amdgcn_s_setprio(1);
#pragma unroll
      for (int ks = 0; ks < 4; ++ks) {
        bf16x8 kf = __builtin_bit_cast(bf16x8,
            *(const int4*)(&Ks[kr * 128 + ((ks*32 + quad*8) ^ ((kr & 7) << 3))]));
        s = __builtin_amdgcn_mfma_f32_16x16x32_bf16(qf[ks], kf, s, 0, 0, 0);
      }
      __builtin_amdgcn_s_setprio(0);
#pragma unroll
      for (int r = 0; r < 4; ++r) {
        float p = __expf(s[r] * scale);
        rs[r] += p;
        int pr = wave*16 + quad*4 + r;
        int pc = ct*16 + l15;
        Ps[pr * 64 + (pc ^ ((pr & 7) << 3))] = bf16rne(p);
      }
    }

    // PV: o[q, d] += P[q, k] V[k, d]
    __builtin_amdgcn_s_setprio(1);
#pragma unroll
    for (int ks2 = 0; ks2 < 2; ++ks2) {
      const int par = wave*16 + l15;
      bf16x8 pa = __builtin_bit_cast(bf16x8,
          *(const int4*)(&Ps[par * 64 + ((ks2*32 + quad*8) ^ ((par & 7) << 3))]));
#pragma unroll
      for (int nb = 0; nb < 8; ++nb) {
        const int vr = nb*16 + l15;
        bf16x8 vb = __builtin_bit_cast(bf16x8,
            *(const int4*)(&Vs[vr * 64 + ((ks2*32 + quad*8) ^ ((vr & 7) << 3))]));
        o[nb] = __builtin_amdgcn_mfma_f32_16x16x32_bf16(pa, vb, o[nb], 0, 0, 0);
      }
    }
    __builtin_amdgcn_s_setprio(0);
    __syncthreads();
  }

  // row sums: reduce across the 16 lanes of each quad
#pragma unroll
  for (int r = 0; r < 4; ++r) {
    float v = rs[r];
    v += __shfl_xor(v, 1);
    v += __shfl_xor(v, 2);
    v += __shfl_xor(v, 4);
    v += __shfl_xor(v, 8);
    rs[r] = v;
  }

  // epilogue: normalize, add DP noise, emit bf16 ctx in [B*S, E] layout
#pragma unroll
  for (int r = 0; r < 4; ++r) {
    float inv = 1.0f / rs[r];
    int sg = q0 + wave*16 + quad*4 + r;
    size_t rowbase = ((size_t)(b * SEQ + sg)) * EMB + h * HD;
#pragma unroll
    for (int nb = 0; nb < 8; ++nb) {
      int e = nb*16 + l15;
      float val = o[nb][r] * inv + noise[rowbase + e] * ns;
      ctxn[rowbase + e] = bf16rne(val);
    }
  }
}

extern "C" void kernel_launch(void* const* d_in, const int* in_sizes, int n_in,
                              void* d_out, int out_size, void* d_ws, size_t ws_size,
                              hipStream_t stream) {
  const float* query = (const float*)d_in[0];
  const float* key_t = (const float*)d_in[1];
  const float* value = (const float*)d_in[2];
  const float* Wq = (const float*)d_in[3];
  const float* bq = (const float*)d_in[4];
  const float* Wk = (const float*)d_in[5];
  const float* bk = (const float*)d_in[6];
  const float* Wv = (const float*)d_in[7];
  const float* bv = (const float*)d_in[8];
  const float* Wo = (const float*)d_in[9];
  const float* bo = (const float*)d_in[10];
  const float* noise = (const float*)d_in[11];

  const size_t SZ_ACT = (size_t)MDIM * KDIM * 2;  // 33,554,432 B
  const size_t SZ_W   = (size_t)NDIM * KDIM * 2;  //  8,388,608 B
  const size_t need_full = 7 * SZ_ACT + 4 * SZ_W; // 256 MB

  char* p = (char*)d_ws;
  ushort *qb, *kb;
  if (ws_size >= need_full) {
    qb = (ushort*)p; p += SZ_ACT;
    kb = (ushort*)p; p += SZ_ACT;
  } else {
    // overlay q/k bf16 inputs on d_out (exactly 64 MB); consumed before final GEMM
    qb = (ushort*)d_out;
    kb = (ushort*)((char*)d_out + SZ_ACT);
  }
  ushort* vb   = (ushort*)p; p += SZ_ACT;
  ushort* wqb  = (ushort*)p; p += SZ_W;
  ushort* wkb  = (ushort*)p; p += SZ_W;
  ushort* wvb  = (ushort*)p; p += SZ_W;
  ushort* wob  = (ushort*)p; p += SZ_W;
  ushort* Qh   = (ushort*)p; p += SZ_ACT;
  ushort* Kh   = (ushort*)p; p += SZ_ACT;
  ushort* Vt   = (ushort*)p; p += SZ_ACT;
  ushort* ctxn = (ushort*)p; p += SZ_ACT;

  const int nAct = MDIM * KDIM;          // 16,777,216
  const int nW   = NDIM * KDIM;          //  4,194,304
  const float NS = (float)sqrt(2.0 * log(1.25 / 1e-5));
  const float SCALE = (float)(1.0 / sqrt((double)HD));

  cvt_bf16<<<dim3(nAct / 1024), dim3(256), 0, stream>>>(query, qb);
  cvt_bf16<<<dim3(nAct / 1024), dim3(256), 0, stream>>>(key_t, kb);
  cvt_bf16<<<dim3(nAct / 1024), dim3(256), 0, stream>>>(value, vb);
  cvt_bf16<<<dim3(nW / 1024),   dim3(256), 0, stream>>>(Wq, wqb);
  cvt_bf16<<<dim3(nW / 1024),   dim3(256), 0, stream>>>(Wk, wkb);
  cvt_bf16<<<dim3(nW / 1024),   dim3(256), 0, stream>>>(Wv, wvb);
  cvt_bf16<<<dim3(nW / 1024),   dim3(256), 0, stream>>>(Wo, wob);

  dim3 ggrid(MDIM / 128, NDIM / 128);   // 64 x 16
  gemm_nt<1><<<ggrid, dim3(256), 0, stream>>>(qb, wqb, bq, (void*)Qh);
  gemm_nt<1><<<ggrid, dim3(256), 0, stream>>>(kb, wkb, bk, (void*)Kh);
  gemm_nt<2><<<ggrid, dim3(256), 0, stream>>>(vb, wvb, bv, (void*)Vt);

  attn_kernel<<<dim3(SEQ / 128, BATCH * NH), dim3(512), 0, stream>>>(
      Qh, Kh, Vt, noise, ctxn, SCALE, NS);

  gemm_nt<0><<<ggrid, dim3(256), 0, stream>>>(ctxn, wob, bo, d_out);
}